// Round 2
// baseline (207.779 us; speedup 1.0000x reference)
//
#include <hip/hip_runtime.h>

#define BB 8
#define CC 128
#define HH 128
#define WW 128
#define PP 32768
#define HWW (HH * WW)

typedef float v4f __attribute__((ext_vector_type(4)));

__device__ inline unsigned short cvt_bf16_rne(float f) {
    unsigned int u = __float_as_uint(f);
    unsigned int r = (u + 0x7fffu + ((u >> 16) & 1u)) >> 16;
    return (unsigned short)r;
}

// ---------------------------------------------------------------------------
// Kernel 1: transpose feat_grid NCHW fp32 -> NHWC bf16 (RNE) into workspace.
// 64 spatial x 128 channels per block (256 B contiguous HBM read per channel).
// XCD-aligned: b = blk & 7, matching the gather's mapping, so the XCD that
// writes batch b's bf16 slice is the one whose L2 serves it in kernel 2.
// LDS: [64][132] fp32 with an XOR-8 column swizzle (keyed on row>>2) that
// reduces the column-write conflict to 4-way while keeping b128 reads clean.
// ---------------------------------------------------------------------------
__global__ __launch_bounds__(256) void transpose_bf16_kernel(
    const float* __restrict__ in,        // [B, C, HW] fp32
    unsigned short* __restrict__ out)    // [B, HW, C] bf16
{
    __shared__ float tile[64][132];
    const int blk = blockIdx.x;          // 0..2047
    const int b = blk & 7;               // XCD-aligned batch
    const int chunk = blk >> 3;          // 0..255
    const int sBase = chunk * 64;
    const int tid = threadIdx.x;

    const float* inb = in + (size_t)b * CC * HWW;
    unsigned short* outb = out + (size_t)b * HWW * CC;

    // Stage: each lane loads 4 consecutive spatial of one channel (v4f, NT —
    // fg is never re-read), writes a 4-row column into LDS with swizzle.
    const int tx = tid & 15;             // spatial float4 index 0..15
    const int c0 = tid >> 4;             // 0..15
    const int xw = (tx & 3) << 3;        // row-group XOR key = ((row>>2)&3)<<3
#pragma unroll
    for (int i = 0; i < 8; ++i) {
        const int c = c0 + 16 * i;
        const v4f v = __builtin_nontemporal_load(
            (const v4f*)(inb + (size_t)c * HWW + sBase + 4 * tx));
        const int xc = c ^ xw;           // swizzled column
#pragma unroll
        for (int j = 0; j < 4; ++j)
            tile[4 * tx + j][xc] = v[j];
    }
    __syncthreads();

    // Drain: lane owns 8 channels of one spatial row -> uint4 (16 B) store;
    // 16 lanes = 256 B contiguous per row.
    const int cx = tid & 15;             // channel-oct index 0..15
    const int s0 = tid >> 4;             // 0..15
#pragma unroll
    for (int i = 0; i < 4; ++i) {
        const int s = s0 + 16 * i;
        const int xv = ((s >> 2) & 3) << 3;
        const int base = (8 * cx) ^ xv;  // multiple of 8: b128-aligned, keeps
                                         // 8-channel group contiguous
        const v4f a = *(const v4f*)&tile[s][base];
        const v4f d = *(const v4f*)&tile[s][base + 4];
        uint4 h;
        h.x = (unsigned)cvt_bf16_rne(a[0]) | ((unsigned)cvt_bf16_rne(a[1]) << 16);
        h.y = (unsigned)cvt_bf16_rne(a[2]) | ((unsigned)cvt_bf16_rne(a[3]) << 16);
        h.z = (unsigned)cvt_bf16_rne(d[0]) | ((unsigned)cvt_bf16_rne(d[1]) << 16);
        h.w = (unsigned)cvt_bf16_rne(d[2]) | ((unsigned)cvt_bf16_rne(d[3]) << 16);
        *(uint4*)(outb + (size_t)(sBase + s) * CC + 8 * cx) = h;
    }
}

// ---------------------------------------------------------------------------
// Corner/weight math (reference semantics): in_bounds on raw x,y; corners
// (f,f),(f,c),(c,f),(c,c); int trunc-remainder then max(,0);
// dinv = 1/(sqrt(d2)+1e-10); OOB -> 0; denom==0 -> 1; normalize.
// ---------------------------------------------------------------------------
__device__ inline void compute_corners(float x, float y,
                                       int gx[4], int gy[4], float wgt[4])
{
    const bool inb = (x >= 0.f) && (y >= 0.f) &&
                     (x <= (float)(WW - 1)) && (y <= (float)(HH - 1));
    const float fx = floorf(x), cx = ceilf(x);
    const float fy = floorf(y), cy = ceilf(y);
    const float corx[4] = {fx, fx, cx, cx};
    const float cory[4] = {fy, cy, fy, cy};
    float denom = 0.f;
#pragma unroll
    for (int k = 0; k < 4; ++k) {
        int gxi = ((int)corx[k]) % WW;
        int gyi = ((int)cory[k]) % HH;
        if (gxi < 0) gxi = 0;
        if (gyi < 0) gyi = 0;
        const float dx = x - (float)gxi;
        const float dy = y - (float)gyi;
        const float dinv = __builtin_amdgcn_rcpf(sqrtf(dx * dx + dy * dy) + 1e-10f);
        const float w = inb ? dinv : 0.f;
        gx[k] = gxi;
        gy[k] = gyi;
        wgt[k] = w;
        denom += w;
    }
    const float rden = (denom == 0.f) ? 1.f : __builtin_amdgcn_rcpf(denom);
#pragma unroll
    for (int k = 0; k < 4; ++k) wgt[k] *= rden;
}

// ---------------------------------------------------------------------------
// Kernel 2: fused weights + gather from bf16 NHWC workspace.
// 16 lanes per point (4 points/wave), lane owns 8 channels -> one uint4
// (b128) load per corner = 256 B contiguous per corner per point-group.
// Corner/weight math recomputed redundantly by all 16 lanes (VALU is free
// under the memory pipe; removes the idx/wgt 16 MiB round-trip, one kernel
// launch, and the dependent idx-load -> gather-load latency chain).
// XCD swizzle: b = blk & 7 keeps batch b's 4 MiB bf16 slice in XCD b's L2;
// output goes out via nontemporal stores so it doesn't thrash that L2.
// ---------------------------------------------------------------------------
__global__ __launch_bounds__(256) void gather_fused_kernel(
    const float* __restrict__ tk,             // [B*P, 2] fp32
    const unsigned short* __restrict__ grid,  // [B, HW, C] bf16
    float* __restrict__ out)                  // [B, P, C] fp32
{
    const int blk = blockIdx.x;               // 0..16383
    const int b = blk & 7;                    // XCD-aligned batch
    const int inner = blk >> 3;               // 0..2047
    const int grp = (int)threadIdx.x >> 4;    // 0..15: point within block
    const int l = (int)threadIdx.x & 15;      // lane within point-group

    const int p = b * PP + inner * 16 + grp;
    const float2 xy = ((const float2*)tk)[p]; // broadcast across 16 lanes

    int gx[4], gy[4];
    float w[4];
    compute_corners(xy.x, xy.y, gx, gy, w);

    const unsigned short* gb = grid + (size_t)b * HWW * CC;
    v4f acc0 = {0.f, 0.f, 0.f, 0.f};
    v4f acc1 = {0.f, 0.f, 0.f, 0.f};
#pragma unroll
    for (int k = 0; k < 4; ++k) {
        const int id = gy[k] * WW + gx[k];
        const uint4 u = *(const uint4*)(gb + (size_t)id * CC + 8 * l);
        v4f v0, v1;
        v0[0] = __uint_as_float(u.x << 16);
        v0[1] = __uint_as_float(u.x & 0xffff0000u);
        v0[2] = __uint_as_float(u.y << 16);
        v0[3] = __uint_as_float(u.y & 0xffff0000u);
        v1[0] = __uint_as_float(u.z << 16);
        v1[1] = __uint_as_float(u.z & 0xffff0000u);
        v1[2] = __uint_as_float(u.w << 16);
        v1[3] = __uint_as_float(u.w & 0xffff0000u);
        acc0 += w[k] * v0;
        acc1 += w[k] * v1;
    }
    v4f* ob = (v4f*)(out + (size_t)p * CC + 8 * l);
    __builtin_nontemporal_store(acc0, ob);
    __builtin_nontemporal_store(acc1, ob + 1);
}

// ---------------------------------------------------------------------------
// Fallback (ws too small): gather straight from NCHW fp32. Correct, slow.
// ---------------------------------------------------------------------------
__global__ __launch_bounds__(256) void gather_nchw_kernel(
    const float* __restrict__ tk,
    const float* __restrict__ grid,      // [B, C, H, W]
    float* __restrict__ out)
{
    const int wave = (int)((blockIdx.x * blockDim.x + threadIdx.x) >> 6);
    const int lane = threadIdx.x & 63;
    if (wave >= BB * PP) return;
    const int b = wave >> 15;

    const float2 xy = ((const float2*)tk)[wave];
    int gx[4], gy[4];
    float wgt[4];
    compute_corners(xy.x, xy.y, gx, gy, wgt);

    const float* gb = grid + (size_t)b * CC * HWW;
    const int c0 = lane * 2;
    float a0 = 0.f, a1 = 0.f;
#pragma unroll
    for (int k = 0; k < 4; ++k) {
        const int sidx = gy[k] * WW + gx[k];
        a0 += wgt[k] * gb[(size_t)c0 * HWW + sidx];
        a1 += wgt[k] * gb[(size_t)(c0 + 1) * HWW + sidx];
    }
    ((float2*)out)[(size_t)wave * (CC / 2) + lane] = make_float2(a0, a1);
}

extern "C" void kernel_launch(void* const* d_in, const int* in_sizes, int n_in,
                              void* d_out, int out_size, void* d_ws, size_t ws_size,
                              hipStream_t stream) {
    const float* tk = (const float*)d_in[0];   // tk_codes [B,P,2] fp32
    const float* fg = (const float*)d_in[1];   // feat_grid [B,C,H,W] fp32
    float* out = (float*)d_out;                // [B,P,C] fp32

    const size_t gridBytes = (size_t)BB * HWW * CC * 2;        // 32 MiB bf16

    if (ws_size >= gridBytes) {
        unsigned short* gbf = (unsigned short*)d_ws;

        // 2048 blocks: 8 batches x 256 chunks of 64 spatial
        transpose_bf16_kernel<<<(BB * HWW) / 64, 256, 0, stream>>>(fg, gbf);
        // 16384 blocks: 16 points/block, 16 lanes/point
        gather_fused_kernel<<<(BB * PP) / 16, 256, 0, stream>>>(tk, gbf, out);
    } else {
        const int blocks = (BB * PP * 64) / 256;
        gather_nchw_kernel<<<blocks, 256, 0, stream>>>(tk, fg, out);
    }
}

// Round 3
// 199.374 us; speedup vs baseline: 1.0422x; 1.0422x over previous
//
#include <hip/hip_runtime.h>

#define BB 8
#define CC 128
#define HH 128
#define WW 128
#define PP 32768
#define HWW (HH * WW)

typedef float v4f __attribute__((ext_vector_type(4)));

__device__ inline unsigned short cvt_bf16_rne(float f) {
    unsigned int u = __float_as_uint(f);
    unsigned int r = (u + 0x7fffu + ((u >> 16) & 1u)) >> 16;
    return (unsigned short)r;
}

// ---------------------------------------------------------------------------
// Kernel 1: transpose feat_grid NCHW fp32 -> NHWC bf16 (RNE) into workspace.
// 64 spatial x 128 channels per block (256 B contiguous HBM read per channel).
// XCD-aligned: b = blk & 7, matching the gather's mapping, so the XCD that
// writes batch b's bf16 slice is the one whose L2 serves it in kernel 3.
// LDS: [64][132] fp32 with an XOR-8 column swizzle (keyed on row>>2).
// ---------------------------------------------------------------------------
__global__ __launch_bounds__(256) void transpose_bf16_kernel(
    const float* __restrict__ in,        // [B, C, HW] fp32
    unsigned short* __restrict__ out)    // [B, HW, C] bf16
{
    __shared__ float tile[64][132];
    const int blk = blockIdx.x;          // 0..2047
    const int b = blk & 7;               // XCD-aligned batch
    const int chunk = blk >> 3;          // 0..255
    const int sBase = chunk * 64;
    const int tid = threadIdx.x;

    const float* inb = in + (size_t)b * CC * HWW;
    unsigned short* outb = out + (size_t)b * HWW * CC;

    const int tx = tid & 15;             // spatial float4 index 0..15
    const int c0 = tid >> 4;             // 0..15
    const int xw = (tx & 3) << 3;        // row-group XOR key = ((row>>2)&3)<<3
#pragma unroll
    for (int i = 0; i < 8; ++i) {
        const int c = c0 + 16 * i;
        const v4f v = __builtin_nontemporal_load(
            (const v4f*)(inb + (size_t)c * HWW + sBase + 4 * tx));
        const int xc = c ^ xw;           // swizzled column
#pragma unroll
        for (int j = 0; j < 4; ++j)
            tile[4 * tx + j][xc] = v[j];
    }
    __syncthreads();

    const int cx = tid & 15;             // channel-oct index 0..15
    const int s0 = tid >> 4;             // 0..15
#pragma unroll
    for (int i = 0; i < 4; ++i) {
        const int s = s0 + 16 * i;
        const int xv = ((s >> 2) & 3) << 3;
        const int base = (8 * cx) ^ xv;  // multiple of 8: b128-aligned
        const v4f a = *(const v4f*)&tile[s][base];
        const v4f d = *(const v4f*)&tile[s][base + 4];
        uint4 h;
        h.x = (unsigned)cvt_bf16_rne(a[0]) | ((unsigned)cvt_bf16_rne(a[1]) << 16);
        h.y = (unsigned)cvt_bf16_rne(a[2]) | ((unsigned)cvt_bf16_rne(a[3]) << 16);
        h.z = (unsigned)cvt_bf16_rne(d[0]) | ((unsigned)cvt_bf16_rne(d[1]) << 16);
        h.w = (unsigned)cvt_bf16_rne(d[2]) | ((unsigned)cvt_bf16_rne(d[3]) << 16);
        *(uint4*)(outb + (size_t)(sBase + s) * CC + 8 * cx) = h;
    }
}

// ---------------------------------------------------------------------------
// Corner/weight math (reference semantics): in_bounds on raw x,y; corners
// (f,f),(f,c),(c,f),(c,c); int trunc-remainder then max(,0);
// dinv = 1/(sqrt(d2)+1e-10); OOB -> 0; denom==0 -> 1; normalize.
// ---------------------------------------------------------------------------
__device__ inline void compute_corners(float x, float y,
                                       int gx[4], int gy[4], float wgt[4])
{
    const bool inb = (x >= 0.f) && (y >= 0.f) &&
                     (x <= (float)(WW - 1)) && (y <= (float)(HH - 1));
    const float fx = floorf(x), cx = ceilf(x);
    const float fy = floorf(y), cy = ceilf(y);
    const float corx[4] = {fx, fx, cx, cx};
    const float cory[4] = {fy, cy, fy, cy};
    float denom = 0.f;
#pragma unroll
    for (int k = 0; k < 4; ++k) {
        int gxi = ((int)corx[k]) % WW;
        int gyi = ((int)cory[k]) % HH;
        if (gxi < 0) gxi = 0;
        if (gyi < 0) gyi = 0;
        const float dx = x - (float)gxi;
        const float dy = y - (float)gyi;
        const float dinv = __builtin_amdgcn_rcpf(sqrtf(dx * dx + dy * dy) + 1e-10f);
        const float w = inb ? dinv : 0.f;
        gx[k] = gxi;
        gy[k] = gyi;
        wgt[k] = w;
        denom += w;
    }
    const float rden = (denom == 0.f) ? 1.f : __builtin_amdgcn_rcpf(denom);
#pragma unroll
    for (int k = 0; k < 4; ++k) wgt[k] *= rden;
}

// ---------------------------------------------------------------------------
// Kernel 2: per-point weight/index precompute. 1 thread = 1 point.
// Indices fit in u16 (0..16383): ushort4 (8 B) instead of int4 halves the
// idx stream. Weights stay fp32 (absmax budget is spent on the bf16 grid).
// ---------------------------------------------------------------------------
__global__ __launch_bounds__(256) void weights_kernel(
    const float* __restrict__ tk,        // [B*P, 2]
    ushort4* __restrict__ idx_out,       // [B*P]
    float4* __restrict__ wgt_out)        // [B*P]
{
    const int p = blockIdx.x * 256 + (int)threadIdx.x;   // exact grid: B*P/256
    const float2 xy = ((const float2*)tk)[p];            // STRIDE==1: no div

    int gx[4], gy[4];
    float wgt[4];
    compute_corners(xy.x, xy.y, gx, gy, wgt);

    ushort4 id;
    id.x = (unsigned short)(gy[0] * WW + gx[0]);
    id.y = (unsigned short)(gy[1] * WW + gx[1]);
    id.z = (unsigned short)(gy[2] * WW + gx[2]);
    id.w = (unsigned short)(gy[3] * WW + gx[3]);
    idx_out[p] = id;
    wgt_out[p] = make_float4(wgt[0], wgt[1], wgt[2], wgt[3]);
}

// ---------------------------------------------------------------------------
// Kernel 3: pure gather from bf16 NHWC workspace using precomputed idx/wgt.
// 2 points/wave, half-wave (32 lanes) per point, lane owns 4 channels
// (uint2 = 8 B bf16x4 per corner; 256 B contiguous per corner per half-wave).
// XCD swizzle: blockIdx.x & 7 selects the batch, so each XCD's 4 MiB L2
// holds exactly its batch's bf16 grid slice.
// ---------------------------------------------------------------------------
__global__ __launch_bounds__(256) void gather_bf16_kernel(
    const unsigned short* __restrict__ grid,  // [B, HW, C] bf16
    const ushort4* __restrict__ idxs,         // [B*P]
    const float4* __restrict__ wgts,          // [B*P]
    float* __restrict__ out)                  // [B, P, C] fp32
{
    const int blk = blockIdx.x;               // 0..32767
    const int b = blk & 7;                    // XCD-aligned batch
    const int inner = blk >> 3;               // 0..4095
    const int wave = (int)threadIdx.x >> 6;   // 0..3
    const int half = ((int)threadIdx.x >> 5) & 1;
    const int sub = (int)threadIdx.x & 31;

    const int p = b * PP + inner * 8 + wave * 2 + half;

    const ushort4 id = idxs[p];               // broadcast 8 B
    const float4 w = wgts[p];

    const unsigned short* gb = grid + (size_t)b * HWW * CC;
    const int idk[4] = {id.x, id.y, id.z, id.w};
    const float wk[4] = {w.x, w.y, w.z, w.w};

    v4f acc = {0.f, 0.f, 0.f, 0.f};
#pragma unroll
    for (int k = 0; k < 4; ++k) {
        const uint2 u = *(const uint2*)(gb + (size_t)idk[k] * CC + 4 * sub);
        v4f v;
        v[0] = __uint_as_float(u.x << 16);
        v[1] = __uint_as_float(u.x & 0xffff0000u);
        v[2] = __uint_as_float(u.y << 16);
        v[3] = __uint_as_float(u.y & 0xffff0000u);
        acc += wk[k] * v;
    }
    __builtin_nontemporal_store(acc, (v4f*)out + (size_t)p * (CC / 4) + sub);
}

// ---------------------------------------------------------------------------
// Fallback (ws too small): gather straight from NCHW fp32. Correct, slow.
// ---------------------------------------------------------------------------
__global__ __launch_bounds__(256) void gather_nchw_kernel(
    const float* __restrict__ tk,
    const float* __restrict__ grid,      // [B, C, H, W]
    float* __restrict__ out)
{
    const int wave = (int)((blockIdx.x * blockDim.x + threadIdx.x) >> 6);
    const int lane = threadIdx.x & 63;
    if (wave >= BB * PP) return;
    const int b = wave >> 15;

    const float2 xy = ((const float2*)tk)[wave];
    int gx[4], gy[4];
    float wgt[4];
    compute_corners(xy.x, xy.y, gx, gy, wgt);

    const float* gb = grid + (size_t)b * CC * HWW;
    const int c0 = lane * 2;
    float a0 = 0.f, a1 = 0.f;
#pragma unroll
    for (int k = 0; k < 4; ++k) {
        const int sidx = gy[k] * WW + gx[k];
        a0 += wgt[k] * gb[(size_t)c0 * HWW + sidx];
        a1 += wgt[k] * gb[(size_t)(c0 + 1) * HWW + sidx];
    }
    ((float2*)out)[(size_t)wave * (CC / 2) + lane] = make_float2(a0, a1);
}

extern "C" void kernel_launch(void* const* d_in, const int* in_sizes, int n_in,
                              void* d_out, int out_size, void* d_ws, size_t ws_size,
                              hipStream_t stream) {
    const float* tk = (const float*)d_in[0];   // tk_codes [B,P,2] fp32
    const float* fg = (const float*)d_in[1];   // feat_grid [B,C,H,W] fp32
    float* out = (float*)d_out;                // [B,P,C] fp32

    const size_t gridBytes = (size_t)BB * HWW * CC * 2;          // 32 MiB bf16
    const size_t idxBytes  = (size_t)BB * PP * sizeof(ushort4);  // 2 MiB
    const size_t wgtBytes  = (size_t)BB * PP * sizeof(float4);   // 4 MiB
    const size_t need = gridBytes + idxBytes + wgtBytes;

    if (ws_size >= need) {
        unsigned short* gbf = (unsigned short*)d_ws;
        ushort4* idxs = (ushort4*)((char*)d_ws + gridBytes);
        float4*  wgts = (float4*)((char*)d_ws + gridBytes + idxBytes);

        // 2048 blocks: 8 batches x 256 chunks of 64 spatial
        transpose_bf16_kernel<<<(BB * HWW) / 64, 256, 0, stream>>>(fg, gbf);
        weights_kernel<<<(BB * PP) / 256, 256, 0, stream>>>(tk, idxs, wgts);
        gather_bf16_kernel<<<(BB * PP) / 8, 256, 0, stream>>>(gbf, idxs, wgts, out);
    } else {
        const int blocks = (BB * PP * 64) / 256;
        gather_nchw_kernel<<<blocks, 256, 0, stream>>>(tk, fg, out);
    }
}